// Round 7
// baseline (892.739 us; speedup 1.0000x reference)
//
#include <hip/hip_runtime.h>

// GraphSAGE 2-layer, N=100000, E=1600000, 128 -> 64 -> 32.
// Round 7: round-6 structure (proven replay-safe) + software-pipelined x/h
// prefetch in the transforms. Round-6 counters: transform1 VGPR=32 ->
// compiler serialized the 4 broadcast loads per k4 (no prefetch regs) ->
// VALUBusy 34%, 137 us. Manual double-buffering gives the scheduler explicit
// next-iteration loads to hoist; live set ~52 regs still fits 64-VGPR
// occupancy (2 blocks/CU at 64KB LDS).

namespace {
constexpr int N = 100000;
constexpr int E = 1600000;
constexpr long long NF64 = (long long)N * 64;   // 6,400,000
constexpr long long NF32 = (long long)N * 32;
constexpr int NBLK = (N + 255) / 256;           // 391 scan blocks
}

// ---------------- CSR build ----------------

// int64 vs int32 edge dtype: high 32-bit words of int64 entries are all zero
// (node ids < 2^31); for int32 data they are random ids. Sample 16384 words,
// single block, one plain store (no atomic storm).
__global__ __launch_bounds__(256) void detect_dtype(const int* __restrict__ raw,
                                                    int* __restrict__ flag) {
    int any = 0;
#pragma unroll
    for (int k = 0; k < 64; ++k) {
        int i = threadIdx.x + k * 256;          // first 16384 qwords
        any |= raw[2 * i + 1];
    }
    unsigned long long b = __ballot(any != 0);
    __shared__ int acc[4];
    int w = threadIdx.x >> 6;
    if ((threadIdx.x & 63) == 0) acc[w] = (b != 0ULL) ? 1 : 0;
    __syncthreads();
    if (threadIdx.x == 0) *flag = acc[0] | acc[1] | acc[2] | acc[3];
}

__global__ void zero_counts(int* __restrict__ counts) {
    int i = blockIdx.x * blockDim.x + threadIdx.x;
    if (i < N) counts[i] = 0;
}

__global__ void count_deg(const int* __restrict__ raw, const int* __restrict__ flag,
                          int* __restrict__ counts) {
    int e = blockIdx.x * blockDim.x + threadIdx.x;
    if (e >= E) return;
    int is32 = *flag;
    int d = is32 ? raw[E + e] : raw[2 * ((long long)E + e)];
    atomicAdd(&counts[d], 1);
}

// Block-local inclusive scan (Hillis-Steele over 256 entries in LDS).
__global__ __launch_bounds__(256) void scan1(const int* __restrict__ counts,
                                             int* __restrict__ rowstart,
                                             int* __restrict__ bsum) {
    __shared__ int tmp[256];
    int t = threadIdx.x;
    int i = blockIdx.x * 256 + t;
    int v = (i < N) ? counts[i] : 0;
    tmp[t] = v;
    __syncthreads();
#pragma unroll
    for (int off = 1; off < 256; off <<= 1) {
        int a = (t >= off) ? tmp[t - off] : 0;
        __syncthreads();
        tmp[t] += a;
        __syncthreads();
    }
    if (i < N) rowstart[i] = tmp[t] - v;          // exclusive within block
    if (t == 255) bsum[blockIdx.x] = tmp[255];    // block total
}

__global__ __launch_bounds__(512) void scan2(int* __restrict__ bsum) {
    __shared__ int tmp[512];
    int t = threadIdx.x;
    int v = (t < NBLK) ? bsum[t] : 0;
    tmp[t] = v;
    __syncthreads();
#pragma unroll
    for (int off = 1; off < 512; off <<= 1) {
        int a = (t >= off) ? tmp[t - off] : 0;
        __syncthreads();
        tmp[t] += a;
        __syncthreads();
    }
    if (t < NBLK) bsum[t] = tmp[t] - v;           // exclusive block offsets
}

__global__ void scan3(int* __restrict__ rowstart, const int* __restrict__ bsum,
                      int* __restrict__ cursor) {
    int i = blockIdx.x * blockDim.x + threadIdx.x;
    if (i < N) {
        rowstart[i] += bsum[i >> 8];
        cursor[i] = 0;                            // counts recycled as cursor
    }
    if (i == 0) rowstart[N] = E;
}

__global__ void fill_csr(const int* __restrict__ raw, const int* __restrict__ flag,
                         const int* __restrict__ rowstart, int* __restrict__ cursor,
                         int* __restrict__ csr) {
    int e = blockIdx.x * blockDim.x + threadIdx.x;
    if (e >= E) return;
    int is32 = *flag;
    int s, d;
    if (is32) {
        s = raw[e];
        d = raw[E + e];
    } else {
        s = raw[2 * (long long)e];
        d = raw[2 * ((long long)E + e)];
    }
    int pos = rowstart[d] + atomicAdd(&cursor[d], 1);
    csr[pos] = s;
}

// ---------------- layer 1 transform: z1 = x@W1l^T, r1 = x@W1r^T ----------------
// W in LDS (single barrier), broadcast x loads double-buffered one k4 ahead.
__global__ __launch_bounds__(1024) void transform1(
        const float* __restrict__ x, const float* __restrict__ W1l,
        const float* __restrict__ W1r, float* __restrict__ z1,
        float* __restrict__ r1) {
    __shared__ float4 wl4[32 * 64];   // wl4[k4*64 + j] = W1l[j][4k4..4k4+3]
    __shared__ float4 wr4[32 * 64];
    const float4* Wl = (const float4*)W1l;   // [64][32] float4
    const float4* Wr = (const float4*)W1r;
    for (int idx = threadIdx.x; idx < 2048; idx += 1024) {
        int j = idx & 63, k4 = idx >> 6;
        wl4[k4 * 64 + j] = Wl[j * 32 + k4];
        wr4[k4 * 64 + j] = Wr[j * 32 + k4];
    }
    __syncthreads();

    const int lane = threadIdx.x & 63;
    const int wid = blockIdx.x * (blockDim.x >> 6) + (threadIdx.x >> 6);
    const int nWaves = gridDim.x * (blockDim.x >> 6);
    const float4* x4 = (const float4*)x;     // [N][32]

    for (int base = wid * 4; base < N; base += nWaves * 4) {   // N % 4 == 0
        const float4* p0 = x4 + (size_t)(base + 0) * 32;
        const float4* p1 = x4 + (size_t)(base + 1) * 32;
        const float4* p2 = x4 + (size_t)(base + 2) * 32;
        const float4* p3 = x4 + (size_t)(base + 3) * 32;
        float a0 = 0.f, a1 = 0.f, a2 = 0.f, a3 = 0.f;
        float b0 = 0.f, b1 = 0.f, b2 = 0.f, b3 = 0.f;
        float4 xc0 = p0[0], xc1 = p1[0], xc2 = p2[0], xc3 = p3[0];
#pragma unroll
        for (int k4 = 0; k4 < 32; ++k4) {
            float4 xn0, xn1, xn2, xn3;
            if (k4 < 31) {                 // compile-time after full unroll
                xn0 = p0[k4 + 1]; xn1 = p1[k4 + 1];
                xn2 = p2[k4 + 1]; xn3 = p3[k4 + 1];
            }
            float4 wlv = wl4[k4 * 64 + lane];
            float4 wrv = wr4[k4 * 64 + lane];
            a0 += wlv.x * xc0.x + wlv.y * xc0.y + wlv.z * xc0.z + wlv.w * xc0.w;
            a1 += wlv.x * xc1.x + wlv.y * xc1.y + wlv.z * xc1.z + wlv.w * xc1.w;
            a2 += wlv.x * xc2.x + wlv.y * xc2.y + wlv.z * xc2.z + wlv.w * xc2.w;
            a3 += wlv.x * xc3.x + wlv.y * xc3.y + wlv.z * xc3.z + wlv.w * xc3.w;
            b0 += wrv.x * xc0.x + wrv.y * xc0.y + wrv.z * xc0.z + wrv.w * xc0.w;
            b1 += wrv.x * xc1.x + wrv.y * xc1.y + wrv.z * xc1.z + wrv.w * xc1.w;
            b2 += wrv.x * xc2.x + wrv.y * xc2.y + wrv.z * xc2.z + wrv.w * xc2.w;
            b3 += wrv.x * xc3.x + wrv.y * xc3.y + wrv.z * xc3.z + wrv.w * xc3.w;
            if (k4 < 31) { xc0 = xn0; xc1 = xn1; xc2 = xn2; xc3 = xn3; }
        }
        size_t o = (size_t)base * 64 + lane;
        z1[o] = a0; z1[o + 64] = a1; z1[o + 128] = a2; z1[o + 192] = a3;
        r1[o] = b0; r1[o + 64] = b1; r1[o + 128] = b2; r1[o + 192] = b3;
    }
}

// ---------------- layer 2 transform: z2 = h@W2l^T, r2 = h@W2r^T ----------------
// Same structure, h loads double-buffered.
__global__ __launch_bounds__(256) void transform2(
        const float* __restrict__ h, const float* __restrict__ W2l,
        const float* __restrict__ W2r, float* __restrict__ z2,
        float* __restrict__ r2) {
    __shared__ float4 wc4[16 * 64];
    const float4* Wl = (const float4*)W2l;   // [32][16] float4
    const float4* Wr = (const float4*)W2r;
    for (int idx = threadIdx.x; idx < 1024; idx += 256) {
        int j = idx & 63, k4 = idx >> 6;
        wc4[k4 * 64 + j] = (j < 32) ? Wl[j * 16 + k4] : Wr[(j - 32) * 16 + k4];
    }
    __syncthreads();

    const int lane = threadIdx.x & 63;
    const int wid = blockIdx.x * (blockDim.x >> 6) + (threadIdx.x >> 6);
    const int nWaves = gridDim.x * (blockDim.x >> 6);
    const float4* h4 = (const float4*)h;     // [N][16]

    for (int base = wid * 4; base < N; base += nWaves * 4) {
        const float4* p0 = h4 + (size_t)(base + 0) * 16;
        const float4* p1 = h4 + (size_t)(base + 1) * 16;
        const float4* p2 = h4 + (size_t)(base + 2) * 16;
        const float4* p3 = h4 + (size_t)(base + 3) * 16;
        float a0 = 0.f, a1 = 0.f, a2 = 0.f, a3 = 0.f;
        float4 hc0 = p0[0], hc1 = p1[0], hc2 = p2[0], hc3 = p3[0];
#pragma unroll
        for (int k4 = 0; k4 < 16; ++k4) {
            float4 hn0, hn1, hn2, hn3;
            if (k4 < 15) {
                hn0 = p0[k4 + 1]; hn1 = p1[k4 + 1];
                hn2 = p2[k4 + 1]; hn3 = p3[k4 + 1];
            }
            float4 wv = wc4[k4 * 64 + lane];
            a0 += wv.x * hc0.x + wv.y * hc0.y + wv.z * hc0.z + wv.w * hc0.w;
            a1 += wv.x * hc1.x + wv.y * hc1.y + wv.z * hc1.z + wv.w * hc1.w;
            a2 += wv.x * hc2.x + wv.y * hc2.y + wv.z * hc2.z + wv.w * hc2.w;
            a3 += wv.x * hc3.x + wv.y * hc3.y + wv.z * hc3.z + wv.w * hc3.w;
            if (k4 < 15) { hc0 = hn0; hc1 = hn1; hc2 = hn2; hc3 = hn3; }
        }
        if (lane < 32) {
            z2[(size_t)(base + 0) * 32 + lane] = a0;
            z2[(size_t)(base + 1) * 32 + lane] = a1;
            z2[(size_t)(base + 2) * 32 + lane] = a2;
            z2[(size_t)(base + 3) * 32 + lane] = a3;
        } else {
            int jj = lane - 32;
            r2[(size_t)(base + 0) * 32 + jj] = a0;
            r2[(size_t)(base + 1) * 32 + jj] = a1;
            r2[(size_t)(base + 2) * 32 + jj] = a2;
            r2[(size_t)(base + 3) * 32 + jj] = a3;
        }
    }
}

// ---------------- fused CSR-gather aggregation ----------------

// Layer 1: wave per node, lane = feature j (64 feats).
__global__ __launch_bounds__(256) void agg1_fused(
        const int* __restrict__ rowstart, const int* __restrict__ csr,
        const float* __restrict__ z1, const float* __restrict__ r1,
        const float* __restrict__ b1, float* __restrict__ h) {
    const int n = blockIdx.x * 4 + (threadIdx.x >> 6);
    if (n >= N) return;
    const int j = threadIdx.x & 63;
    const int beg = rowstart[n], end = rowstart[n + 1];
    float s = 0.f;
    int p = beg;
    for (; p + 4 <= end; p += 4) {
        int c0 = csr[p], c1 = csr[p + 1], c2 = csr[p + 2], c3 = csr[p + 3];
        s += z1[(size_t)c0 * 64 + j] + z1[(size_t)c1 * 64 + j]
           + z1[(size_t)c2 * 64 + j] + z1[(size_t)c3 * 64 + j];
    }
    for (; p < end; ++p) s += z1[(size_t)csr[p] * 64 + j];
    float m = (end > beg) ? s / (float)(end - beg) : 0.f;
    size_t o = (size_t)n * 64 + j;
    h[o] = fmaxf(m + b1[j] + r1[o], 0.f);
}

// Layer 2: half-wave per node (32 feats), wave handles 2 nodes.
__global__ __launch_bounds__(256) void agg2_fused(
        const int* __restrict__ rowstart, const int* __restrict__ csr,
        const float* __restrict__ z2, const float* __restrict__ r2,
        const float* __restrict__ b2, float* __restrict__ out) {
    const int wid = blockIdx.x * 4 + (threadIdx.x >> 6);
    const int n = wid * 2 + ((threadIdx.x >> 5) & 1);
    if (n >= N) return;
    const int j = threadIdx.x & 31;
    const int beg = rowstart[n], end = rowstart[n + 1];
    float s = 0.f;
    int p = beg;
    for (; p + 4 <= end; p += 4) {
        int c0 = csr[p], c1 = csr[p + 1], c2 = csr[p + 2], c3 = csr[p + 3];
        s += z2[(size_t)c0 * 32 + j] + z2[(size_t)c1 * 32 + j]
           + z2[(size_t)c2 * 32 + j] + z2[(size_t)c3 * 32 + j];
    }
    for (; p < end; ++p) s += z2[(size_t)csr[p] * 32 + j];
    float m = (end > beg) ? s / (float)(end - beg) : 0.f;
    size_t o = (size_t)n * 32 + j;
    out[o] = m + b2[j] + r2[o];
}

// ---------------- launch ----------------

extern "C" void kernel_launch(void* const* d_in, const int* in_sizes, int n_in,
                              void* d_out, int out_size, void* d_ws, size_t ws_size,
                              hipStream_t stream) {
    const float* x    = (const float*)d_in[0];
    const int*   raw  = (const int*)d_in[1];
    const float* W1l  = (const float*)d_in[2];
    const float* b1   = (const float*)d_in[3];
    const float* W1r  = (const float*)d_in[4];
    const float* W2l  = (const float*)d_in[5];
    const float* b2   = (const float*)d_in[6];
    const float* W2r  = (const float*)d_in[7];
    float* out = (float*)d_out;

    float* ws = (float*)d_ws;
    float* z1 = ws;                    // [N*64]
    float* r1 = ws + NF64;             // [N*64]
    float* h  = ws + 2 * NF64;         // [N*64]
    float* z2 = ws;                    // reuse z1 space [N*32]
    float* r2 = ws + NF32;             // reuse z1 space [N*32]

    int* ibase    = (int*)(ws + 3 * NF64);
    int* counts   = ibase;                   // [N], recycled as cursor
    int* rowstart = ibase + N;               // [N+1]
    int* bsum     = ibase + 2 * N + 1;       // [512]
    int* csr      = ibase + 2 * N + 1 + 512; // [E]
    int* flag     = csr + E;                 // [1]

    const int eb = (E + 255) / 256;

    detect_dtype<<<1, 256, 0, stream>>>(raw, flag);
    zero_counts<<<NBLK, 256, 0, stream>>>(counts);
    count_deg<<<eb, 256, 0, stream>>>(raw, flag, counts);
    scan1<<<NBLK, 256, 0, stream>>>(counts, rowstart, bsum);
    scan2<<<1, 512, 0, stream>>>(bsum);
    scan3<<<NBLK, 256, 0, stream>>>(rowstart, bsum, counts);
    fill_csr<<<eb, 256, 0, stream>>>(raw, flag, rowstart, counts, csr);

    transform1<<<512, 1024, 0, stream>>>(x, W1l, W1r, z1, r1);
    agg1_fused<<<(N + 3) / 4, 256, 0, stream>>>(rowstart, csr, z1, r1, b1, h);

    transform2<<<2048, 256, 0, stream>>>(h, W2l, W2r, z2, r2);
    agg2_fused<<<(N + 7) / 8, 256, 0, stream>>>(rowstart, csr, z2, r2, b2, out);
}

// Round 8
// 469.367 us; speedup vs baseline: 1.9020x; 1.9020x over previous
//
#include <hip/hip_runtime.h>

// GraphSAGE 2-layer, N=100000, E=1600000, 128 -> 64 -> 32.
// Round 8: round-6 structure exactly (replay-proven), with two knobs to fix
// transform1's latency-boundedness WITHOUT the round-7 spill:
//   - __launch_bounds__(1024, 1): lifts the implicit VGPR cap 64 -> 128
//   - #pragma unroll 4 on the k4 loop: bounded load batching (16 loads in
//     flight ~ 92 live regs < 128, vs round-7's unbounded hoist -> spill)
// Round-7 evidence: VGPR=64 + 1.31 GB hbm_bytes (17x logical) = scratch
// spill; round-6: VGPR=32, loads serialized, VALUBusy 34%.

namespace {
constexpr int N = 100000;
constexpr int E = 1600000;
constexpr long long NF64 = (long long)N * 64;   // 6,400,000
constexpr long long NF32 = (long long)N * 32;
constexpr int NBLK = (N + 255) / 256;           // 391 scan blocks
}

// ---------------- CSR build ----------------

// int64 vs int32 edge dtype: high 32-bit words of int64 entries are all zero
// (node ids < 2^31); for int32 data they are random ids. Sample 16384 words,
// single block, one plain store (no atomic storm).
__global__ __launch_bounds__(256) void detect_dtype(const int* __restrict__ raw,
                                                    int* __restrict__ flag) {
    int any = 0;
#pragma unroll
    for (int k = 0; k < 64; ++k) {
        int i = threadIdx.x + k * 256;          // first 16384 qwords
        any |= raw[2 * i + 1];
    }
    unsigned long long b = __ballot(any != 0);
    __shared__ int acc[4];
    int w = threadIdx.x >> 6;
    if ((threadIdx.x & 63) == 0) acc[w] = (b != 0ULL) ? 1 : 0;
    __syncthreads();
    if (threadIdx.x == 0) *flag = acc[0] | acc[1] | acc[2] | acc[3];
}

__global__ void zero_counts(int* __restrict__ counts) {
    int i = blockIdx.x * blockDim.x + threadIdx.x;
    if (i < N) counts[i] = 0;
}

__global__ void count_deg(const int* __restrict__ raw, const int* __restrict__ flag,
                          int* __restrict__ counts) {
    int e = blockIdx.x * blockDim.x + threadIdx.x;
    if (e >= E) return;
    int is32 = *flag;
    int d = is32 ? raw[E + e] : raw[2 * ((long long)E + e)];
    atomicAdd(&counts[d], 1);
}

// Block-local inclusive scan (Hillis-Steele over 256 entries in LDS).
__global__ __launch_bounds__(256) void scan1(const int* __restrict__ counts,
                                             int* __restrict__ rowstart,
                                             int* __restrict__ bsum) {
    __shared__ int tmp[256];
    int t = threadIdx.x;
    int i = blockIdx.x * 256 + t;
    int v = (i < N) ? counts[i] : 0;
    tmp[t] = v;
    __syncthreads();
#pragma unroll
    for (int off = 1; off < 256; off <<= 1) {
        int a = (t >= off) ? tmp[t - off] : 0;
        __syncthreads();
        tmp[t] += a;
        __syncthreads();
    }
    if (i < N) rowstart[i] = tmp[t] - v;          // exclusive within block
    if (t == 255) bsum[blockIdx.x] = tmp[255];    // block total
}

__global__ __launch_bounds__(512) void scan2(int* __restrict__ bsum) {
    __shared__ int tmp[512];
    int t = threadIdx.x;
    int v = (t < NBLK) ? bsum[t] : 0;
    tmp[t] = v;
    __syncthreads();
#pragma unroll
    for (int off = 1; off < 512; off <<= 1) {
        int a = (t >= off) ? tmp[t - off] : 0;
        __syncthreads();
        tmp[t] += a;
        __syncthreads();
    }
    if (t < NBLK) bsum[t] = tmp[t] - v;           // exclusive block offsets
}

__global__ void scan3(int* __restrict__ rowstart, const int* __restrict__ bsum,
                      int* __restrict__ cursor) {
    int i = blockIdx.x * blockDim.x + threadIdx.x;
    if (i < N) {
        rowstart[i] += bsum[i >> 8];
        cursor[i] = 0;                            // counts recycled as cursor
    }
    if (i == 0) rowstart[N] = E;
}

__global__ void fill_csr(const int* __restrict__ raw, const int* __restrict__ flag,
                         const int* __restrict__ rowstart, int* __restrict__ cursor,
                         int* __restrict__ csr) {
    int e = blockIdx.x * blockDim.x + threadIdx.x;
    if (e >= E) return;
    int is32 = *flag;
    int s, d;
    if (is32) {
        s = raw[e];
        d = raw[E + e];
    } else {
        s = raw[2 * (long long)e];
        d = raw[2 * ((long long)E + e)];
    }
    int pos = rowstart[d] + atomicAdd(&cursor[d], 1);
    csr[pos] = s;
}

// ---------------- layer 1 transform: z1 = x@W1l^T, r1 = x@W1r^T ----------------
// W in LDS (single barrier), u=4 broadcast x loads, bounded unroll-4 so the
// scheduler batches 16 loads in flight under the (1024,1) 128-VGPR cap.
__global__ __launch_bounds__(1024, 1) void transform1(
        const float* __restrict__ x, const float* __restrict__ W1l,
        const float* __restrict__ W1r, float* __restrict__ z1,
        float* __restrict__ r1) {
    __shared__ float4 wl4[32 * 64];   // wl4[k4*64 + j] = W1l[j][4k4..4k4+3]
    __shared__ float4 wr4[32 * 64];
    const float4* Wl = (const float4*)W1l;   // [64][32] float4
    const float4* Wr = (const float4*)W1r;
    for (int idx = threadIdx.x; idx < 2048; idx += 1024) {
        int j = idx & 63, k4 = idx >> 6;
        wl4[k4 * 64 + j] = Wl[j * 32 + k4];
        wr4[k4 * 64 + j] = Wr[j * 32 + k4];
    }
    __syncthreads();

    const int lane = threadIdx.x & 63;
    const int wid = blockIdx.x * (blockDim.x >> 6) + (threadIdx.x >> 6);
    const int nWaves = gridDim.x * (blockDim.x >> 6);
    const float4* x4 = (const float4*)x;     // [N][32]

    for (int base = wid * 4; base < N; base += nWaves * 4) {   // N % 4 == 0
        const float4* p0 = x4 + (size_t)(base + 0) * 32;
        const float4* p1 = x4 + (size_t)(base + 1) * 32;
        const float4* p2 = x4 + (size_t)(base + 2) * 32;
        const float4* p3 = x4 + (size_t)(base + 3) * 32;
        float a0 = 0.f, a1 = 0.f, a2 = 0.f, a3 = 0.f;
        float b0 = 0.f, b1 = 0.f, b2 = 0.f, b3 = 0.f;
#pragma unroll 4
        for (int k4 = 0; k4 < 32; ++k4) {
            float4 x0 = p0[k4];
            float4 x1 = p1[k4];
            float4 x2 = p2[k4];
            float4 x3 = p3[k4];
            float4 wlv = wl4[k4 * 64 + lane];
            float4 wrv = wr4[k4 * 64 + lane];
            a0 += wlv.x * x0.x + wlv.y * x0.y + wlv.z * x0.z + wlv.w * x0.w;
            a1 += wlv.x * x1.x + wlv.y * x1.y + wlv.z * x1.z + wlv.w * x1.w;
            a2 += wlv.x * x2.x + wlv.y * x2.y + wlv.z * x2.z + wlv.w * x2.w;
            a3 += wlv.x * x3.x + wlv.y * x3.y + wlv.z * x3.z + wlv.w * x3.w;
            b0 += wrv.x * x0.x + wrv.y * x0.y + wrv.z * x0.z + wrv.w * x0.w;
            b1 += wrv.x * x1.x + wrv.y * x1.y + wrv.z * x1.z + wrv.w * x1.w;
            b2 += wrv.x * x2.x + wrv.y * x2.y + wrv.z * x2.z + wrv.w * x2.w;
            b3 += wrv.x * x3.x + wrv.y * x3.y + wrv.z * x3.z + wrv.w * x3.w;
        }
        size_t o = (size_t)base * 64 + lane;
        z1[o] = a0; z1[o + 64] = a1; z1[o + 128] = a2; z1[o + 192] = a3;
        r1[o] = b0; r1[o + 64] = b1; r1[o + 128] = b2; r1[o + 192] = b3;
    }
}

// ---------------- layer 2 transform: z2 = h@W2l^T, r2 = h@W2r^T ----------------
// Same structure; unroll-4 bounds hoisting (round-3's unbounded version hit
// VGPR=256).
__global__ __launch_bounds__(256) void transform2(
        const float* __restrict__ h, const float* __restrict__ W2l,
        const float* __restrict__ W2r, float* __restrict__ z2,
        float* __restrict__ r2) {
    __shared__ float4 wc4[16 * 64];
    const float4* Wl = (const float4*)W2l;   // [32][16] float4
    const float4* Wr = (const float4*)W2r;
    for (int idx = threadIdx.x; idx < 1024; idx += 256) {
        int j = idx & 63, k4 = idx >> 6;
        wc4[k4 * 64 + j] = (j < 32) ? Wl[j * 16 + k4] : Wr[(j - 32) * 16 + k4];
    }
    __syncthreads();

    const int lane = threadIdx.x & 63;
    const int wid = blockIdx.x * (blockDim.x >> 6) + (threadIdx.x >> 6);
    const int nWaves = gridDim.x * (blockDim.x >> 6);
    const float4* h4 = (const float4*)h;     // [N][16]

    for (int base = wid * 4; base < N; base += nWaves * 4) {
        const float4* p0 = h4 + (size_t)(base + 0) * 16;
        const float4* p1 = h4 + (size_t)(base + 1) * 16;
        const float4* p2 = h4 + (size_t)(base + 2) * 16;
        const float4* p3 = h4 + (size_t)(base + 3) * 16;
        float a0 = 0.f, a1 = 0.f, a2 = 0.f, a3 = 0.f;
#pragma unroll 4
        for (int k4 = 0; k4 < 16; ++k4) {
            float4 h0 = p0[k4];
            float4 h1 = p1[k4];
            float4 h2 = p2[k4];
            float4 h3 = p3[k4];
            float4 wv = wc4[k4 * 64 + lane];
            a0 += wv.x * h0.x + wv.y * h0.y + wv.z * h0.z + wv.w * h0.w;
            a1 += wv.x * h1.x + wv.y * h1.y + wv.z * h1.z + wv.w * h1.w;
            a2 += wv.x * h2.x + wv.y * h2.y + wv.z * h2.z + wv.w * h2.w;
            a3 += wv.x * h3.x + wv.y * h3.y + wv.z * h3.z + wv.w * h3.w;
        }
        if (lane < 32) {
            z2[(size_t)(base + 0) * 32 + lane] = a0;
            z2[(size_t)(base + 1) * 32 + lane] = a1;
            z2[(size_t)(base + 2) * 32 + lane] = a2;
            z2[(size_t)(base + 3) * 32 + lane] = a3;
        } else {
            int jj = lane - 32;
            r2[(size_t)(base + 0) * 32 + jj] = a0;
            r2[(size_t)(base + 1) * 32 + jj] = a1;
            r2[(size_t)(base + 2) * 32 + jj] = a2;
            r2[(size_t)(base + 3) * 32 + jj] = a3;
        }
    }
}

// ---------------- fused CSR-gather aggregation ----------------

// Layer 1: wave per node, lane = feature j (64 feats).
__global__ __launch_bounds__(256) void agg1_fused(
        const int* __restrict__ rowstart, const int* __restrict__ csr,
        const float* __restrict__ z1, const float* __restrict__ r1,
        const float* __restrict__ b1, float* __restrict__ h) {
    const int n = blockIdx.x * 4 + (threadIdx.x >> 6);
    if (n >= N) return;
    const int j = threadIdx.x & 63;
    const int beg = rowstart[n], end = rowstart[n + 1];
    float s = 0.f;
    int p = beg;
    for (; p + 4 <= end; p += 4) {
        int c0 = csr[p], c1 = csr[p + 1], c2 = csr[p + 2], c3 = csr[p + 3];
        s += z1[(size_t)c0 * 64 + j] + z1[(size_t)c1 * 64 + j]
           + z1[(size_t)c2 * 64 + j] + z1[(size_t)c3 * 64 + j];
    }
    for (; p < end; ++p) s += z1[(size_t)csr[p] * 64 + j];
    float m = (end > beg) ? s / (float)(end - beg) : 0.f;
    size_t o = (size_t)n * 64 + j;
    h[o] = fmaxf(m + b1[j] + r1[o], 0.f);
}

// Layer 2: half-wave per node (32 feats), wave handles 2 nodes.
__global__ __launch_bounds__(256) void agg2_fused(
        const int* __restrict__ rowstart, const int* __restrict__ csr,
        const float* __restrict__ z2, const float* __restrict__ r2,
        const float* __restrict__ b2, float* __restrict__ out) {
    const int wid = blockIdx.x * 4 + (threadIdx.x >> 6);
    const int n = wid * 2 + ((threadIdx.x >> 5) & 1);
    if (n >= N) return;
    const int j = threadIdx.x & 31;
    const int beg = rowstart[n], end = rowstart[n + 1];
    float s = 0.f;
    int p = beg;
    for (; p + 4 <= end; p += 4) {
        int c0 = csr[p], c1 = csr[p + 1], c2 = csr[p + 2], c3 = csr[p + 3];
        s += z2[(size_t)c0 * 32 + j] + z2[(size_t)c1 * 32 + j]
           + z2[(size_t)c2 * 32 + j] + z2[(size_t)c3 * 32 + j];
    }
    for (; p < end; ++p) s += z2[(size_t)csr[p] * 32 + j];
    float m = (end > beg) ? s / (float)(end - beg) : 0.f;
    size_t o = (size_t)n * 32 + j;
    out[o] = m + b2[j] + r2[o];
}

// ---------------- launch ----------------

extern "C" void kernel_launch(void* const* d_in, const int* in_sizes, int n_in,
                              void* d_out, int out_size, void* d_ws, size_t ws_size,
                              hipStream_t stream) {
    const float* x    = (const float*)d_in[0];
    const int*   raw  = (const int*)d_in[1];
    const float* W1l  = (const float*)d_in[2];
    const float* b1   = (const float*)d_in[3];
    const float* W1r  = (const float*)d_in[4];
    const float* W2l  = (const float*)d_in[5];
    const float* b2   = (const float*)d_in[6];
    const float* W2r  = (const float*)d_in[7];
    float* out = (float*)d_out;

    float* ws = (float*)d_ws;
    float* z1 = ws;                    // [N*64]
    float* r1 = ws + NF64;             // [N*64]
    float* h  = ws + 2 * NF64;         // [N*64]
    float* z2 = ws;                    // reuse z1 space [N*32]
    float* r2 = ws + NF32;             // reuse z1 space [N*32]

    int* ibase    = (int*)(ws + 3 * NF64);
    int* counts   = ibase;                   // [N], recycled as cursor
    int* rowstart = ibase + N;               // [N+1]
    int* bsum     = ibase + 2 * N + 1;       // [512]
    int* csr      = ibase + 2 * N + 1 + 512; // [E]
    int* flag     = csr + E;                 // [1]

    const int eb = (E + 255) / 256;

    detect_dtype<<<1, 256, 0, stream>>>(raw, flag);
    zero_counts<<<NBLK, 256, 0, stream>>>(counts);
    count_deg<<<eb, 256, 0, stream>>>(raw, flag, counts);
    scan1<<<NBLK, 256, 0, stream>>>(counts, rowstart, bsum);
    scan2<<<1, 512, 0, stream>>>(bsum);
    scan3<<<NBLK, 256, 0, stream>>>(rowstart, bsum, counts);
    fill_csr<<<eb, 256, 0, stream>>>(raw, flag, rowstart, counts, csr);

    transform1<<<512, 1024, 0, stream>>>(x, W1l, W1r, z1, r1);
    agg1_fused<<<(N + 3) / 4, 256, 0, stream>>>(rowstart, csr, z1, r1, b1, h);

    transform2<<<2048, 256, 0, stream>>>(h, W2l, W2r, z2, r2);
    agg2_fused<<<(N + 7) / 8, 256, 0, stream>>>(rowstart, csr, z2, r2, b2, out);
}

// Round 9
// 345.750 us; speedup vs baseline: 2.5820x; 1.3575x over previous
//
#include <hip/hip_runtime.h>

// GraphSAGE 2-layer, N=100000, E=1600000, 128 -> 64 -> 32.
// Round 9: transforms moved to MFMA (bf16 in, f32 accum). Rounds 6-8 proved
// the VALU broadcast-load structure is stuck latency-bound at ~137 us
// (VALUBusy 33%, hipcc won't pipeline the loads). MFMA 16x16x32_bf16 makes
// the transforms memory-bound (~20 us): W fragments persist in registers,
// A fragments are 8 coalesced dwordx4 + cvt per 16-node tile, 16 MFMAs/tile.
// Fragment layouts per cdna4_isa §10 / CDNA3 ISA (K=32 family):
//   A: lane l -> A[l&15][(l>>4)*8 + j]
//   B: lane l -> B[(l>>4)*8 + j][l&15]
//   D: lane l -> D[(l>>4)*4 + reg][l&15]   (HW-verified m89/m91)
// bf16 rounding error ~1e-3 abs vs threshold 2.84e-2 (current absmax 3.9e-3).
// CSR build + agg kernels byte-identical to round 8 (replay-proven).

namespace {
constexpr int N = 100000;
constexpr int E = 1600000;
constexpr long long NF64 = (long long)N * 64;   // 6,400,000
constexpr long long NF32 = (long long)N * 32;
constexpr int NBLK = (N + 255) / 256;           // 391 scan blocks
constexpr int NT16 = N / 16;                    // 6250 node tiles (exact)
}

using bf16x8 = __attribute__((ext_vector_type(8))) short;
using f32x4  = __attribute__((ext_vector_type(4))) float;

__device__ __forceinline__ short f2bf(float f) {
    unsigned u = __builtin_bit_cast(unsigned, f);
    u += 0x7FFFu + ((u >> 16) & 1u);            // RNE truncate to bf16
    return (short)(u >> 16);
}

__device__ __forceinline__ bf16x8 load_frag8(const float* __restrict__ p) {
    const float4* p4 = (const float4*)p;        // p is 32B-aligned by construction
    float4 f0 = p4[0], f1 = p4[1];
    bf16x8 r;
    r[0] = f2bf(f0.x); r[1] = f2bf(f0.y); r[2] = f2bf(f0.z); r[3] = f2bf(f0.w);
    r[4] = f2bf(f1.x); r[5] = f2bf(f1.y); r[6] = f2bf(f1.z); r[7] = f2bf(f1.w);
    return r;
}

// ---------------- CSR build ----------------

// int64 vs int32 edge dtype: high 32-bit words of int64 entries are all zero
// (node ids < 2^31); for int32 data they are random ids. Sample 16384 words,
// single block, one plain store (no atomic storm).
__global__ __launch_bounds__(256) void detect_dtype(const int* __restrict__ raw,
                                                    int* __restrict__ flag) {
    int any = 0;
#pragma unroll
    for (int k = 0; k < 64; ++k) {
        int i = threadIdx.x + k * 256;          // first 16384 qwords
        any |= raw[2 * i + 1];
    }
    unsigned long long b = __ballot(any != 0);
    __shared__ int acc[4];
    int w = threadIdx.x >> 6;
    if ((threadIdx.x & 63) == 0) acc[w] = (b != 0ULL) ? 1 : 0;
    __syncthreads();
    if (threadIdx.x == 0) *flag = acc[0] | acc[1] | acc[2] | acc[3];
}

__global__ void zero_counts(int* __restrict__ counts) {
    int i = blockIdx.x * blockDim.x + threadIdx.x;
    if (i < N) counts[i] = 0;
}

__global__ void count_deg(const int* __restrict__ raw, const int* __restrict__ flag,
                          int* __restrict__ counts) {
    int e = blockIdx.x * blockDim.x + threadIdx.x;
    if (e >= E) return;
    int is32 = *flag;
    int d = is32 ? raw[E + e] : raw[2 * ((long long)E + e)];
    atomicAdd(&counts[d], 1);
}

// Block-local inclusive scan (Hillis-Steele over 256 entries in LDS).
__global__ __launch_bounds__(256) void scan1(const int* __restrict__ counts,
                                             int* __restrict__ rowstart,
                                             int* __restrict__ bsum) {
    __shared__ int tmp[256];
    int t = threadIdx.x;
    int i = blockIdx.x * 256 + t;
    int v = (i < N) ? counts[i] : 0;
    tmp[t] = v;
    __syncthreads();
#pragma unroll
    for (int off = 1; off < 256; off <<= 1) {
        int a = (t >= off) ? tmp[t - off] : 0;
        __syncthreads();
        tmp[t] += a;
        __syncthreads();
    }
    if (i < N) rowstart[i] = tmp[t] - v;          // exclusive within block
    if (t == 255) bsum[blockIdx.x] = tmp[255];    // block total
}

__global__ __launch_bounds__(512) void scan2(int* __restrict__ bsum) {
    __shared__ int tmp[512];
    int t = threadIdx.x;
    int v = (t < NBLK) ? bsum[t] : 0;
    tmp[t] = v;
    __syncthreads();
#pragma unroll
    for (int off = 1; off < 512; off <<= 1) {
        int a = (t >= off) ? tmp[t - off] : 0;
        __syncthreads();
        tmp[t] += a;
        __syncthreads();
    }
    if (t < NBLK) bsum[t] = tmp[t] - v;           // exclusive block offsets
}

__global__ void scan3(int* __restrict__ rowstart, const int* __restrict__ bsum,
                      int* __restrict__ cursor) {
    int i = blockIdx.x * blockDim.x + threadIdx.x;
    if (i < N) {
        rowstart[i] += bsum[i >> 8];
        cursor[i] = 0;                            // counts recycled as cursor
    }
    if (i == 0) rowstart[N] = E;
}

__global__ void fill_csr(const int* __restrict__ raw, const int* __restrict__ flag,
                         const int* __restrict__ rowstart, int* __restrict__ cursor,
                         int* __restrict__ csr) {
    int e = blockIdx.x * blockDim.x + threadIdx.x;
    if (e >= E) return;
    int is32 = *flag;
    int s, d;
    if (is32) {
        s = raw[e];
        d = raw[E + e];
    } else {
        s = raw[2 * (long long)e];
        d = raw[2 * ((long long)E + e)];
    }
    int pos = rowstart[d] + atomicAdd(&cursor[d], 1);
    csr[pos] = s;
}

// ---------------- layer 1 transform (MFMA): z1 = x@W1l^T, r1 = x@W1r^T ----------------
// Wave handles node-tile t and column half q (cols q*32..q*32+31) of BOTH
// matrices. W fragments persist in registers across the tile loop.
__global__ __launch_bounds__(256) void transform1_mfma(
        const float* __restrict__ x, const float* __restrict__ W1l,
        const float* __restrict__ W1r, float* __restrict__ z1,
        float* __restrict__ r1) {
    const int lane = threadIdx.x & 63;
    const int gw = blockIdx.x * 4 + (threadIdx.x >> 6);
    const int q = gw & 1;
    const int r16 = lane & 15;
    const int kgrp = lane >> 4;                  // 0..3

    bf16x8 wf[2][2][4];                          // [mat][coltile][kb]
#pragma unroll
    for (int m = 0; m < 2; ++m) {
        const float* W = m ? W1r : W1l;
#pragma unroll
        for (int c = 0; c < 2; ++c) {
            const float* pw = W + (size_t)(q * 32 + c * 16 + r16) * 128 + kgrp * 8;
#pragma unroll
            for (int kb = 0; kb < 4; ++kb)
                wf[m][c][kb] = load_frag8(pw + kb * 32);
        }
    }

    const int stride = (gridDim.x * 4) >> 1;
    for (int t = gw >> 1; t < NT16; t += stride) {
        const float* px = x + ((size_t)t * 16 + r16) * 128 + kgrp * 8;
        bf16x8 af[4];
#pragma unroll
        for (int kb = 0; kb < 4; ++kb) af[kb] = load_frag8(px + kb * 32);

        f32x4 a00 = {0.f,0.f,0.f,0.f}, a01 = {0.f,0.f,0.f,0.f};
        f32x4 a10 = {0.f,0.f,0.f,0.f}, a11 = {0.f,0.f,0.f,0.f};
#pragma unroll
        for (int kb = 0; kb < 4; ++kb) {
            a00 = __builtin_amdgcn_mfma_f32_16x16x32_bf16(af[kb], wf[0][0][kb], a00, 0, 0, 0);
            a01 = __builtin_amdgcn_mfma_f32_16x16x32_bf16(af[kb], wf[0][1][kb], a01, 0, 0, 0);
            a10 = __builtin_amdgcn_mfma_f32_16x16x32_bf16(af[kb], wf[1][0][kb], a10, 0, 0, 0);
            a11 = __builtin_amdgcn_mfma_f32_16x16x32_bf16(af[kb], wf[1][1][kb], a11, 0, 0, 0);
        }
#pragma unroll
        for (int i = 0; i < 4; ++i) {
            size_t row = (size_t)t * 16 + kgrp * 4 + i;
            z1[row * 64 + q * 32 +  0 + r16] = a00[i];
            z1[row * 64 + q * 32 + 16 + r16] = a01[i];
            r1[row * 64 + q * 32 +  0 + r16] = a10[i];
            r1[row * 64 + q * 32 + 16 + r16] = a11[i];
        }
    }
}

// ---------------- layer 2 transform (MFMA): z2 = h@W2l^T, r2 = h@W2r^T ----------------
// Wave handles node-tile t, all 32 output cols of both matrices (K=64 -> 2 kb).
__global__ __launch_bounds__(256) void transform2_mfma(
        const float* __restrict__ h, const float* __restrict__ W2l,
        const float* __restrict__ W2r, float* __restrict__ z2,
        float* __restrict__ r2) {
    const int lane = threadIdx.x & 63;
    const int gw = blockIdx.x * 4 + (threadIdx.x >> 6);
    const int r16 = lane & 15;
    const int kgrp = lane >> 4;

    bf16x8 wf[2][2][2];                          // [mat][coltile][kb]
#pragma unroll
    for (int m = 0; m < 2; ++m) {
        const float* W = m ? W2r : W2l;
#pragma unroll
        for (int c = 0; c < 2; ++c) {
            const float* pw = W + (size_t)(c * 16 + r16) * 64 + kgrp * 8;
#pragma unroll
            for (int kb = 0; kb < 2; ++kb)
                wf[m][c][kb] = load_frag8(pw + kb * 32);
        }
    }

    for (int t = gw; t < NT16; t += gridDim.x * 4) {
        const float* ph = h + ((size_t)t * 16 + r16) * 64 + kgrp * 8;
        bf16x8 af[2];
        af[0] = load_frag8(ph);
        af[1] = load_frag8(ph + 32);

        f32x4 a00 = {0.f,0.f,0.f,0.f}, a01 = {0.f,0.f,0.f,0.f};
        f32x4 a10 = {0.f,0.f,0.f,0.f}, a11 = {0.f,0.f,0.f,0.f};
#pragma unroll
        for (int kb = 0; kb < 2; ++kb) {
            a00 = __builtin_amdgcn_mfma_f32_16x16x32_bf16(af[kb], wf[0][0][kb], a00, 0, 0, 0);
            a01 = __builtin_amdgcn_mfma_f32_16x16x32_bf16(af[kb], wf[0][1][kb], a01, 0, 0, 0);
            a10 = __builtin_amdgcn_mfma_f32_16x16x32_bf16(af[kb], wf[1][0][kb], a10, 0, 0, 0);
            a11 = __builtin_amdgcn_mfma_f32_16x16x32_bf16(af[kb], wf[1][1][kb], a11, 0, 0, 0);
        }
#pragma unroll
        for (int i = 0; i < 4; ++i) {
            size_t row = (size_t)t * 16 + kgrp * 4 + i;
            z2[row * 32 +  0 + r16] = a00[i];
            z2[row * 32 + 16 + r16] = a01[i];
            r2[row * 32 +  0 + r16] = a10[i];
            r2[row * 32 + 16 + r16] = a11[i];
        }
    }
}

// ---------------- fused CSR-gather aggregation ----------------

// Layer 1: wave per node, lane = feature j (64 feats).
__global__ __launch_bounds__(256) void agg1_fused(
        const int* __restrict__ rowstart, const int* __restrict__ csr,
        const float* __restrict__ z1, const float* __restrict__ r1,
        const float* __restrict__ b1, float* __restrict__ h) {
    const int n = blockIdx.x * 4 + (threadIdx.x >> 6);
    if (n >= N) return;
    const int j = threadIdx.x & 63;
    const int beg = rowstart[n], end = rowstart[n + 1];
    float s = 0.f;
    int p = beg;
    for (; p + 4 <= end; p += 4) {
        int c0 = csr[p], c1 = csr[p + 1], c2 = csr[p + 2], c3 = csr[p + 3];
        s += z1[(size_t)c0 * 64 + j] + z1[(size_t)c1 * 64 + j]
           + z1[(size_t)c2 * 64 + j] + z1[(size_t)c3 * 64 + j];
    }
    for (; p < end; ++p) s += z1[(size_t)csr[p] * 64 + j];
    float m = (end > beg) ? s / (float)(end - beg) : 0.f;
    size_t o = (size_t)n * 64 + j;
    h[o] = fmaxf(m + b1[j] + r1[o], 0.f);
}

// Layer 2: half-wave per node (32 feats), wave handles 2 nodes.
__global__ __launch_bounds__(256) void agg2_fused(
        const int* __restrict__ rowstart, const int* __restrict__ csr,
        const float* __restrict__ z2, const float* __restrict__ r2,
        const float* __restrict__ b2, float* __restrict__ out) {
    const int wid = blockIdx.x * 4 + (threadIdx.x >> 6);
    const int n = wid * 2 + ((threadIdx.x >> 5) & 1);
    if (n >= N) return;
    const int j = threadIdx.x & 31;
    const int beg = rowstart[n], end = rowstart[n + 1];
    float s = 0.f;
    int p = beg;
    for (; p + 4 <= end; p += 4) {
        int c0 = csr[p], c1 = csr[p + 1], c2 = csr[p + 2], c3 = csr[p + 3];
        s += z2[(size_t)c0 * 32 + j] + z2[(size_t)c1 * 32 + j]
           + z2[(size_t)c2 * 32 + j] + z2[(size_t)c3 * 32 + j];
    }
    for (; p < end; ++p) s += z2[(size_t)csr[p] * 32 + j];
    float m = (end > beg) ? s / (float)(end - beg) : 0.f;
    size_t o = (size_t)n * 32 + j;
    out[o] = m + b2[j] + r2[o];
}

// ---------------- launch ----------------

extern "C" void kernel_launch(void* const* d_in, const int* in_sizes, int n_in,
                              void* d_out, int out_size, void* d_ws, size_t ws_size,
                              hipStream_t stream) {
    const float* x    = (const float*)d_in[0];
    const int*   raw  = (const int*)d_in[1];
    const float* W1l  = (const float*)d_in[2];
    const float* b1   = (const float*)d_in[3];
    const float* W1r  = (const float*)d_in[4];
    const float* W2l  = (const float*)d_in[5];
    const float* b2   = (const float*)d_in[6];
    const float* W2r  = (const float*)d_in[7];
    float* out = (float*)d_out;

    float* ws = (float*)d_ws;
    float* z1 = ws;                    // [N*64]
    float* r1 = ws + NF64;             // [N*64]
    float* h  = ws + 2 * NF64;         // [N*64]
    float* z2 = ws;                    // reuse z1 space [N*32]
    float* r2 = ws + NF32;             // reuse z1 space [N*32]

    int* ibase    = (int*)(ws + 3 * NF64);
    int* counts   = ibase;                   // [N], recycled as cursor
    int* rowstart = ibase + N;               // [N+1]
    int* bsum     = ibase + 2 * N + 1;       // [512]
    int* csr      = ibase + 2 * N + 1 + 512; // [E]
    int* flag     = csr + E;                 // [1]

    const int eb = (E + 255) / 256;

    detect_dtype<<<1, 256, 0, stream>>>(raw, flag);
    zero_counts<<<NBLK, 256, 0, stream>>>(counts);
    count_deg<<<eb, 256, 0, stream>>>(raw, flag, counts);
    scan1<<<NBLK, 256, 0, stream>>>(counts, rowstart, bsum);
    scan2<<<1, 512, 0, stream>>>(bsum);
    scan3<<<NBLK, 256, 0, stream>>>(rowstart, bsum, counts);
    fill_csr<<<eb, 256, 0, stream>>>(raw, flag, rowstart, counts, csr);

    transform1_mfma<<<1024, 256, 0, stream>>>(x, W1l, W1r, z1, r1);
    agg1_fused<<<(N + 3) / 4, 256, 0, stream>>>(rowstart, csr, z1, r1, b1, h);

    transform2_mfma<<<1024, 256, 0, stream>>>(h, W2l, W2r, z2, r2);
    agg2_fused<<<(N + 7) / 8, 256, 0, stream>>>(rowstart, csr, z2, r2, b2, out);
}

// Round 10
// 314.944 us; speedup vs baseline: 2.8346x; 1.0978x over previous
//
#include <hip/hip_runtime.h>

// GraphSAGE 2-layer, N=100000, E=1600000, 128 -> 64 -> 32.
// Round 10: fill_csr rewritten as dst-chunked filter. Round-9 counters:
// WRITE_SIZE=107MB = E x 64B (one full line per random 4B csr write, no
// merging across XCD L2s, ~950 GB/s effective). 8 chunks of 12500 nodes:
// each pass's csr writes land in an 800KB L2-resident window and merge;
// the 8x re-read of the edge stream is cheap sequential traffic (~100MB).
// All other kernels byte-identical to round 9 (MFMA transforms + CSR gather).

namespace {
constexpr int N = 100000;
constexpr int E = 1600000;
constexpr long long NF64 = (long long)N * 64;   // 6,400,000
constexpr long long NF32 = (long long)N * 32;
constexpr int NBLK = (N + 255) / 256;           // 391 scan blocks
constexpr int NT16 = N / 16;                    // 6250 node tiles (exact)
constexpr int NCHUNK = 8;                       // 12500 nodes per chunk
constexpr int CHUNK_N = N / NCHUNK;
constexpr int BPC = 128;                        // blocks per chunk
}

using bf16x8 = __attribute__((ext_vector_type(8))) short;
using f32x4  = __attribute__((ext_vector_type(4))) float;

__device__ __forceinline__ short f2bf(float f) {
    unsigned u = __builtin_bit_cast(unsigned, f);
    u += 0x7FFFu + ((u >> 16) & 1u);            // RNE truncate to bf16
    return (short)(u >> 16);
}

__device__ __forceinline__ bf16x8 load_frag8(const float* __restrict__ p) {
    const float4* p4 = (const float4*)p;
    float4 f0 = p4[0], f1 = p4[1];
    bf16x8 r;
    r[0] = f2bf(f0.x); r[1] = f2bf(f0.y); r[2] = f2bf(f0.z); r[3] = f2bf(f0.w);
    r[4] = f2bf(f1.x); r[5] = f2bf(f1.y); r[6] = f2bf(f1.z); r[7] = f2bf(f1.w);
    return r;
}

// ---------------- CSR build ----------------

// int64 vs int32 edge dtype: sample 16384 high words, single block, one store.
__global__ __launch_bounds__(256) void detect_dtype(const int* __restrict__ raw,
                                                    int* __restrict__ flag) {
    int any = 0;
#pragma unroll
    for (int k = 0; k < 64; ++k) {
        int i = threadIdx.x + k * 256;          // first 16384 qwords
        any |= raw[2 * i + 1];
    }
    unsigned long long b = __ballot(any != 0);
    __shared__ int acc[4];
    int w = threadIdx.x >> 6;
    if ((threadIdx.x & 63) == 0) acc[w] = (b != 0ULL) ? 1 : 0;
    __syncthreads();
    if (threadIdx.x == 0) *flag = acc[0] | acc[1] | acc[2] | acc[3];
}

__global__ void zero_counts(int* __restrict__ counts) {
    int i = blockIdx.x * blockDim.x + threadIdx.x;
    if (i < N) counts[i] = 0;
}

__global__ void count_deg(const int* __restrict__ raw, const int* __restrict__ flag,
                          int* __restrict__ counts) {
    int e = blockIdx.x * blockDim.x + threadIdx.x;
    if (e >= E) return;
    int is32 = *flag;
    int d = is32 ? raw[E + e] : raw[2 * ((long long)E + e)];
    atomicAdd(&counts[d], 1);
}

// Block-local inclusive scan (Hillis-Steele over 256 entries in LDS).
__global__ __launch_bounds__(256) void scan1(const int* __restrict__ counts,
                                             int* __restrict__ rowstart,
                                             int* __restrict__ bsum) {
    __shared__ int tmp[256];
    int t = threadIdx.x;
    int i = blockIdx.x * 256 + t;
    int v = (i < N) ? counts[i] : 0;
    tmp[t] = v;
    __syncthreads();
#pragma unroll
    for (int off = 1; off < 256; off <<= 1) {
        int a = (t >= off) ? tmp[t - off] : 0;
        __syncthreads();
        tmp[t] += a;
        __syncthreads();
    }
    if (i < N) rowstart[i] = tmp[t] - v;          // exclusive within block
    if (t == 255) bsum[blockIdx.x] = tmp[255];    // block total
}

__global__ __launch_bounds__(512) void scan2(int* __restrict__ bsum) {
    __shared__ int tmp[512];
    int t = threadIdx.x;
    int v = (t < NBLK) ? bsum[t] : 0;
    tmp[t] = v;
    __syncthreads();
#pragma unroll
    for (int off = 1; off < 512; off <<= 1) {
        int a = (t >= off) ? tmp[t - off] : 0;
        __syncthreads();
        tmp[t] += a;
        __syncthreads();
    }
    if (t < NBLK) bsum[t] = tmp[t] - v;           // exclusive block offsets
}

__global__ void scan3(int* __restrict__ rowstart, const int* __restrict__ bsum,
                      int* __restrict__ cursor) {
    int i = blockIdx.x * blockDim.x + threadIdx.x;
    if (i < N) {
        rowstart[i] += bsum[i >> 8];
        cursor[i] = 0;                            // counts recycled as cursor
    }
    if (i == 0) rowstart[N] = E;
}

// Dst-chunked CSR fill: chunk c handles d in [c*12500, (c+1)*12500); its csr
// writes land in a contiguous ~800KB window (L2-resident -> writes merge).
__global__ __launch_bounds__(256) void fill_csr_chunked(
        const int* __restrict__ raw, const int* __restrict__ flag,
        const int* __restrict__ rowstart, int* __restrict__ cursor,
        int* __restrict__ csr) {
    const int chunk = blockIdx.x / BPC;
    const int bsl   = blockIdx.x - chunk * BPC;
    const int lo = chunk * CHUNK_N, hi = lo + CHUNK_N;
    const int is32 = *flag;
    for (int e = bsl * 256 + threadIdx.x; e < E; e += BPC * 256) {
        int d = is32 ? raw[E + e] : raw[2 * ((long long)E + e)];
        if (d < lo || d >= hi) continue;
        int s = is32 ? raw[e] : raw[2 * (long long)e];
        int pos = rowstart[d] + atomicAdd(&cursor[d], 1);
        csr[pos] = s;
    }
}

// ---------------- layer 1 transform (MFMA): z1 = x@W1l^T, r1 = x@W1r^T ----------------
__global__ __launch_bounds__(256) void transform1_mfma(
        const float* __restrict__ x, const float* __restrict__ W1l,
        const float* __restrict__ W1r, float* __restrict__ z1,
        float* __restrict__ r1) {
    const int lane = threadIdx.x & 63;
    const int gw = blockIdx.x * 4 + (threadIdx.x >> 6);
    const int q = gw & 1;
    const int r16 = lane & 15;
    const int kgrp = lane >> 4;                  // 0..3

    bf16x8 wf[2][2][4];                          // [mat][coltile][kb]
#pragma unroll
    for (int m = 0; m < 2; ++m) {
        const float* W = m ? W1r : W1l;
#pragma unroll
        for (int c = 0; c < 2; ++c) {
            const float* pw = W + (size_t)(q * 32 + c * 16 + r16) * 128 + kgrp * 8;
#pragma unroll
            for (int kb = 0; kb < 4; ++kb)
                wf[m][c][kb] = load_frag8(pw + kb * 32);
        }
    }

    const int stride = (gridDim.x * 4) >> 1;
    for (int t = gw >> 1; t < NT16; t += stride) {
        const float* px = x + ((size_t)t * 16 + r16) * 128 + kgrp * 8;
        bf16x8 af[4];
#pragma unroll
        for (int kb = 0; kb < 4; ++kb) af[kb] = load_frag8(px + kb * 32);

        f32x4 a00 = {0.f,0.f,0.f,0.f}, a01 = {0.f,0.f,0.f,0.f};
        f32x4 a10 = {0.f,0.f,0.f,0.f}, a11 = {0.f,0.f,0.f,0.f};
#pragma unroll
        for (int kb = 0; kb < 4; ++kb) {
            a00 = __builtin_amdgcn_mfma_f32_16x16x32_bf16(af[kb], wf[0][0][kb], a00, 0, 0, 0);
            a01 = __builtin_amdgcn_mfma_f32_16x16x32_bf16(af[kb], wf[0][1][kb], a01, 0, 0, 0);
            a10 = __builtin_amdgcn_mfma_f32_16x16x32_bf16(af[kb], wf[1][0][kb], a10, 0, 0, 0);
            a11 = __builtin_amdgcn_mfma_f32_16x16x32_bf16(af[kb], wf[1][1][kb], a11, 0, 0, 0);
        }
#pragma unroll
        for (int i = 0; i < 4; ++i) {
            size_t row = (size_t)t * 16 + kgrp * 4 + i;
            z1[row * 64 + q * 32 +  0 + r16] = a00[i];
            z1[row * 64 + q * 32 + 16 + r16] = a01[i];
            r1[row * 64 + q * 32 +  0 + r16] = a10[i];
            r1[row * 64 + q * 32 + 16 + r16] = a11[i];
        }
    }
}

// ---------------- layer 2 transform (MFMA): z2 = h@W2l^T, r2 = h@W2r^T ----------------
__global__ __launch_bounds__(256) void transform2_mfma(
        const float* __restrict__ h, const float* __restrict__ W2l,
        const float* __restrict__ W2r, float* __restrict__ z2,
        float* __restrict__ r2) {
    const int lane = threadIdx.x & 63;
    const int gw = blockIdx.x * 4 + (threadIdx.x >> 6);
    const int r16 = lane & 15;
    const int kgrp = lane >> 4;

    bf16x8 wf[2][2][2];                          // [mat][coltile][kb]
#pragma unroll
    for (int m = 0; m < 2; ++m) {
        const float* W = m ? W2r : W2l;
#pragma unroll
        for (int c = 0; c < 2; ++c) {
            const float* pw = W + (size_t)(c * 16 + r16) * 64 + kgrp * 8;
#pragma unroll
            for (int kb = 0; kb < 2; ++kb)
                wf[m][c][kb] = load_frag8(pw + kb * 32);
        }
    }

    for (int t = gw; t < NT16; t += gridDim.x * 4) {
        const float* ph = h + ((size_t)t * 16 + r16) * 64 + kgrp * 8;
        bf16x8 af[2];
        af[0] = load_frag8(ph);
        af[1] = load_frag8(ph + 32);

        f32x4 a00 = {0.f,0.f,0.f,0.f}, a01 = {0.f,0.f,0.f,0.f};
        f32x4 a10 = {0.f,0.f,0.f,0.f}, a11 = {0.f,0.f,0.f,0.f};
#pragma unroll
        for (int kb = 0; kb < 2; ++kb) {
            a00 = __builtin_amdgcn_mfma_f32_16x16x32_bf16(af[kb], wf[0][0][kb], a00, 0, 0, 0);
            a01 = __builtin_amdgcn_mfma_f32_16x16x32_bf16(af[kb], wf[0][1][kb], a01, 0, 0, 0);
            a10 = __builtin_amdgcn_mfma_f32_16x16x32_bf16(af[kb], wf[1][0][kb], a10, 0, 0, 0);
            a11 = __builtin_amdgcn_mfma_f32_16x16x32_bf16(af[kb], wf[1][1][kb], a11, 0, 0, 0);
        }
#pragma unroll
        for (int i = 0; i < 4; ++i) {
            size_t row = (size_t)t * 16 + kgrp * 4 + i;
            z2[row * 32 +  0 + r16] = a00[i];
            z2[row * 32 + 16 + r16] = a01[i];
            r2[row * 32 +  0 + r16] = a10[i];
            r2[row * 32 + 16 + r16] = a11[i];
        }
    }
}

// ---------------- fused CSR-gather aggregation ----------------

// Layer 1: wave per node, lane = feature j (64 feats).
__global__ __launch_bounds__(256) void agg1_fused(
        const int* __restrict__ rowstart, const int* __restrict__ csr,
        const float* __restrict__ z1, const float* __restrict__ r1,
        const float* __restrict__ b1, float* __restrict__ h) {
    const int n = blockIdx.x * 4 + (threadIdx.x >> 6);
    if (n >= N) return;
    const int j = threadIdx.x & 63;
    const int beg = rowstart[n], end = rowstart[n + 1];
    float s = 0.f;
    int p = beg;
    for (; p + 4 <= end; p += 4) {
        int c0 = csr[p], c1 = csr[p + 1], c2 = csr[p + 2], c3 = csr[p + 3];
        s += z1[(size_t)c0 * 64 + j] + z1[(size_t)c1 * 64 + j]
           + z1[(size_t)c2 * 64 + j] + z1[(size_t)c3 * 64 + j];
    }
    for (; p < end; ++p) s += z1[(size_t)csr[p] * 64 + j];
    float m = (end > beg) ? s / (float)(end - beg) : 0.f;
    size_t o = (size_t)n * 64 + j;
    h[o] = fmaxf(m + b1[j] + r1[o], 0.f);
}

// Layer 2: half-wave per node (32 feats), wave handles 2 nodes.
__global__ __launch_bounds__(256) void agg2_fused(
        const int* __restrict__ rowstart, const int* __restrict__ csr,
        const float* __restrict__ z2, const float* __restrict__ r2,
        const float* __restrict__ b2, float* __restrict__ out) {
    const int wid = blockIdx.x * 4 + (threadIdx.x >> 6);
    const int n = wid * 2 + ((threadIdx.x >> 5) & 1);
    if (n >= N) return;
    const int j = threadIdx.x & 31;
    const int beg = rowstart[n], end = rowstart[n + 1];
    float s = 0.f;
    int p = beg;
    for (; p + 4 <= end; p += 4) {
        int c0 = csr[p], c1 = csr[p + 1], c2 = csr[p + 2], c3 = csr[p + 3];
        s += z2[(size_t)c0 * 32 + j] + z2[(size_t)c1 * 32 + j]
           + z2[(size_t)c2 * 32 + j] + z2[(size_t)c3 * 32 + j];
    }
    for (; p < end; ++p) s += z2[(size_t)csr[p] * 32 + j];
    float m = (end > beg) ? s / (float)(end - beg) : 0.f;
    size_t o = (size_t)n * 32 + j;
    out[o] = m + b2[j] + r2[o];
}

// ---------------- launch ----------------

extern "C" void kernel_launch(void* const* d_in, const int* in_sizes, int n_in,
                              void* d_out, int out_size, void* d_ws, size_t ws_size,
                              hipStream_t stream) {
    const float* x    = (const float*)d_in[0];
    const int*   raw  = (const int*)d_in[1];
    const float* W1l  = (const float*)d_in[2];
    const float* b1   = (const float*)d_in[3];
    const float* W1r  = (const float*)d_in[4];
    const float* W2l  = (const float*)d_in[5];
    const float* b2   = (const float*)d_in[6];
    const float* W2r  = (const float*)d_in[7];
    float* out = (float*)d_out;

    float* ws = (float*)d_ws;
    float* z1 = ws;                    // [N*64]
    float* r1 = ws + NF64;             // [N*64]
    float* h  = ws + 2 * NF64;         // [N*64]
    float* z2 = ws;                    // reuse z1 space [N*32]
    float* r2 = ws + NF32;             // reuse z1 space [N*32]

    int* ibase    = (int*)(ws + 3 * NF64);
    int* counts   = ibase;                   // [N], recycled as cursor
    int* rowstart = ibase + N;               // [N+1]
    int* bsum     = ibase + 2 * N + 1;       // [512]
    int* csr      = ibase + 2 * N + 1 + 512; // [E]
    int* flag     = csr + E;                 // [1]

    const int eb = (E + 255) / 256;

    detect_dtype<<<1, 256, 0, stream>>>(raw, flag);
    zero_counts<<<NBLK, 256, 0, stream>>>(counts);
    count_deg<<<eb, 256, 0, stream>>>(raw, flag, counts);
    scan1<<<NBLK, 256, 0, stream>>>(counts, rowstart, bsum);
    scan2<<<1, 512, 0, stream>>>(bsum);
    scan3<<<NBLK, 256, 0, stream>>>(rowstart, bsum, counts);
    fill_csr_chunked<<<NCHUNK * BPC, 256, 0, stream>>>(raw, flag, rowstart, counts, csr);

    transform1_mfma<<<1024, 256, 0, stream>>>(x, W1l, W1r, z1, r1);
    agg1_fused<<<(N + 3) / 4, 256, 0, stream>>>(rowstart, csr, z1, r1, b1, h);

    transform2_mfma<<<1024, 256, 0, stream>>>(h, W2l, W2r, z2, r2);
    agg2_fused<<<(N + 7) / 8, 256, 0, stream>>>(rowstart, csr, z2, r2, b2, out);
}